// Round 7
// baseline (1139.293 us; speedup 1.0000x reference)
//
#include <hip/hip_runtime.h>

#define B_  128
#define T_  256
#define D_  256
#define U_  256
#define TU  768      // 3*U
#define TC  64       // timestep chunk
#define NC  (T_/TC)  // 4 chunks

__device__ __forceinline__ float sigm(float x) { return 1.f / (1.f + __expf(-x)); }

// tanh via __expf: tanh(x) = 1 - 2/(e^{2x}+1). (absmax unchanged since R2)
__device__ __forceinline__ float tanh_fast(float x) {
    float e = __expf(2.f * x);
    return 1.f - 2.f / (e + 1.f);
}

// direct cubic B-spline eval: grid cells [g_j, g_j+0.4), g_j = -2.2 + 0.4*j, j=0..10
// nonzero basis m = j-3..j (clipped to 0..7); coeffs at ksw_lds[u*9 + m]
__device__ __forceinline__ float spline_eval(float x, const float* __restrict__ ksw_lds, int u) {
    float xc = (x + 2.2f) * 2.5f;
    float fj = floorf(xc);
    int   j  = (int)fj;
    float tl = xc - fj;
    float t2 = tl * tl, t3 = t2 * tl;
    float om = 1.f - tl;
    const float S = 1.f / 6.f;
    float w0 = om * om * om * S;                            // m = j-3
    float w1 = (3.f * t3 - 6.f * t2 + 4.f) * S;             // m = j-2
    float w2 = (-3.f * t3 + 3.f * t2 + 3.f * tl + 1.f) * S; // m = j-1
    float w3 = t3 * S;                                      // m = j
    bool  v  = (j >= 0) && (j <= 10);
    float r  = 0.f;
#pragma unroll
    for (int k = 0; k < 4; ++k) {
        int   m  = j - 3 + k;
        bool  ok = v && (m >= 0) && (m <= 7);
        int   mc = min(max(m, 0), 7);
        float wk = (k == 0) ? w0 : (k == 1) ? w1 : (k == 2) ? w2 : w3;
        float cf = ksw_lds[u * 9 + mc];
        r += ok ? wk * cf : 0.f;
    }
    return r;
}

// ---------------- K0: zero recurrent state + init exchange flags ----------------
__global__ void k0_init(float* __restrict__ wh, float* __restrict__ wc,
                        float* __restrict__ wsub, int* __restrict__ flags) {
    int i = blockIdx.x * 256 + threadIdx.x;          // grid 128 -> 32768
    wh[i] = 0.f;
    wc[i] = 0.f;
    if (i < 3 * B_) wsub[i] = 0.f;
    if (i < 4 * B_) flags[i] = -1;                   // [B][2 r][2 half]
}

// ---------------- K1: A[b][tl][j] = x[b, t0+tl, :] @ kernel + bias ----------------
// ROUND 7 REWRITE: old 64x64-tile version ran 57 us (36% of fp32 peak; 230 us of
// the 1093 total). New: 128x192 tile, 256 threads, 8x12 acc/thread, BK=32.
// Grid = (8192/128)x(768/192) = 64x4 = 256 blocks = EXACTLY 1/CU, one round.
// Per k-iter: 5 ds_read_b128 per 96 FMA (vs 2 per 16 before). LDS ~42 KB.
// __launch_bounds__(256,1) pins reg budget to 512/wave (acc 96 + operands fits;
// do NOT let the allocator target high occupancy and spill -- R3 lesson).
#define M1 128
#define N1 192
#define K1 32
__global__ __launch_bounds__(256, 1) void k1_gemm(const float* __restrict__ X,
                                                  const float* __restrict__ Km,
                                                  const float* __restrict__ bias,
                                                  float* __restrict__ A, int t0) {
    __shared__ float Xs[K1][M1 + 4];   // [32][132]; +4 pad (row stride 528B = 33*16 ok)
    __shared__ float Ks[K1][N1 + 4];   // [32][196]; row stride 784B = 49*16 ok
    const int tid = threadIdx.x;
    const int bm  = blockIdx.x * M1;
    const int bn  = blockIdx.y * N1;

    // compute mapping: 16x16 thread grid, each 8 rows x 12 cols
    const int ty = tid >> 4, tx = tid & 15;
    const int m0 = ty * 8, n0 = tx * 12;

    // X staging: row lr (0..127), k-half kq in {0,16}; 4 float4 per thread
    const int lr = tid >> 1, kq = (tid & 1) * 16;
    const int rr = bm + lr;
    const int xb = rr >> 6, xtl = rr & 63;
    const float* xrow = X + (size_t)(xb * T_ + t0 + xtl) * D_;

    // K staging: k-row kr (0..31), col group nq (0..168 step 24); 6 float4 per thread
    const int kr = tid >> 3, nq = (tid & 7) * 24;

    float acc[8][12] = {};
    for (int kb = 0; kb < 256; kb += K1) {
#pragma unroll
        for (int i = 0; i < 4; ++i) {
            float4 v = *(const float4*)(xrow + kb + kq + i * 4);
            Xs[kq + i * 4 + 0][lr] = v.x;
            Xs[kq + i * 4 + 1][lr] = v.y;
            Xs[kq + i * 4 + 2][lr] = v.z;
            Xs[kq + i * 4 + 3][lr] = v.w;
        }
#pragma unroll
        for (int i = 0; i < 6; ++i)
            *(float4*)&Ks[kr][nq + i * 4] =
                *(const float4*)(Km + (size_t)(kb + kr) * TU + bn + nq + i * 4);
        __syncthreads();
#pragma unroll 4
        for (int k = 0; k < K1; ++k) {
            float a[8], bb[12];
            *(float4*)&a[0]  = *(const float4*)&Xs[k][m0];
            *(float4*)&a[4]  = *(const float4*)&Xs[k][m0 + 4];
            *(float4*)&bb[0] = *(const float4*)&Ks[k][n0];
            *(float4*)&bb[4] = *(const float4*)&Ks[k][n0 + 4];
            *(float4*)&bb[8] = *(const float4*)&Ks[k][n0 + 8];
#pragma unroll
            for (int i = 0; i < 8; ++i)
#pragma unroll
                for (int j = 0; j < 12; ++j)
                    acc[i][j] = fmaf(a[i], bb[j], acc[i][j]);
        }
        __syncthreads();
    }
#pragma unroll
    for (int j4 = 0; j4 < 3; ++j4) {
        float4 bv = *(const float4*)(bias + bn + n0 + j4 * 4);
#pragma unroll
        for (int i = 0; i < 8; ++i) {
            float4 o;
            o.x = acc[i][j4 * 4 + 0] + bv.x;
            o.y = acc[i][j4 * 4 + 1] + bv.y;
            o.z = acc[i][j4 * 4 + 2] + bv.z;
            o.w = acc[i][j4 * 4 + 3] + bv.w;
            *(float4*)(A + (size_t)(bm + m0 + i) * TU + bn + n0 + j4 * 4) = o;
        }
    }
}

// ---------------- K2: pair-split recurrence, R stationary in regs ----------------
// R6 structure (214 us) + round-7 surgery:
//  * 2 barriers/step: phase C (gates) merged into phase A of the next step.
//    CA(tl) = {gates(t0+tl-1)+publish [pstate]; KAN(t0+tl) [all]; poll h(t0+tl-1)
//    [waves 6,7]; x(t0+tl+1) issue [waves 1,2,3,5]}; B(tl) = {GEMV + KANred +
//    xstage}. Dep check: gates need zred/so_l from B(tl-1); KAN needs subs/xs
//    from B(tl-1); both ordered by syncB.
//  * GEMV h-broadcast via uniform-address ds_read_b128 (16 reads, LDS-pipe,
//    broadcast) instead of 64 v_readlane (VALU) -> 192 FMA + 16 DS vs 256 VALU.
//  * KAN u1 duty moved OFF pstate waves (to waves 1,2,3,5) -> publish path
//    shorter; A-prefetch issued AFTER the flag store so the publish vmcnt(0)
//    covers only the 64 xh stores.
__global__ __launch_bounds__(512, 2)
void k2_rec(const float* __restrict__ A,
            const float* __restrict__ X,
            const float* __restrict__ R,
            const float* __restrict__ stk,
            const float* __restrict__ strk,
            const float* __restrict__ aggw,
            const float* __restrict__ aggb,
            const float* __restrict__ kbw,
            const float* __restrict__ ksw,
            float* __restrict__ out,
            float* __restrict__ ws_h,
            float* __restrict__ ws_c,
            float* __restrict__ ws_sub,
            float* __restrict__ xh,    // [B][2][256]
            int* __restrict__ flags,   // [B][2 r][2 half]
            int t0) {
    __shared__ float hs[256];
    __shared__ float xs[256];
    __shared__ float zred[8][64][3];
    __shared__ float kred[768];
    __shared__ float so_l[3];
    __shared__ float subs[3];
    __shared__ float st2[6];
    __shared__ float hhist[TC][128];        // 32 KB h history -> epilogue bulk write
    __shared__ float ksw_lds[768 * 9];

    const int tid  = threadIdx.x;
    const int lane = tid & 63;
    const int w    = tid >> 6;
    const int p    = w & 3;
    const int c    = ((w >> 2) << 6) | lane;   // 0..127
    const int b    = blockIdx.x & 127;
    const int r    = blockIdx.x >> 7;
    const int ui   = r * 128 + c;              // global output-unit index
    const bool pstate = (p == 0);              // waves 0 and 4 hold gate state

    // ---- stationary R fragment (lives in unified VGPR/AGPR file) ----
    float Rf[3][64];
#pragma unroll
    for (int g = 0; g < 3; ++g)
#pragma unroll
        for (int uu = 0; uu < 64; ++uu)
            Rf[g][uu] = R[(size_t)(p * 64 + uu) * TU + g * 256 + ui];

    // ---- KAN duties ----
    // u0 = tid for ALL threads. u1 (units 512..767) + x-prefetch: waves 1,2,3,5.
    const int s0 = tid >> 8, d0 = tid & 255;
    const float skx0 = strk[s0 * 512 + d0];
    const float skh0 = strk[s0 * 512 + 256 + d0];
    const float bw0  = kbw[tid];
    int u1i = -1;
    if (tid >= 64 && tid < 256)       u1i = tid - 64;    // waves 1-3 -> 0..191
    else if (tid >= 320 && tid < 384) u1i = tid - 128;   // wave 5    -> 192..255
    float skx1 = 0.f, skh1 = 0.f, bw1 = 0.f;
    if (u1i >= 0) {
        skx1 = strk[2 * 512 + u1i];
        skh1 = strk[2 * 512 + 256 + u1i];
        bw1  = kbw[512 + u1i];
    }

    const float aw0 = aggw[ui], aw1 = aggw[256 + ui], aw2 = aggw[512 + ui], ab = aggb[ui];
    float c_reg = ws_c[b * 256 + ui];

    for (int i = tid; i < 768 * 8; i += 512) ksw_lds[(i >> 3) * 9 + (i & 7)] = ksw[i];
    if (tid < 256) hs[tid] = ws_h[b * 256 + tid];
    if (tid < 256) xs[tid] = X[((size_t)b * T_ + t0) * D_ + tid];
    if (tid < 3)   subs[tid] = ws_sub[b * 3 + tid];
    if (tid < 6)   st2[tid] = stk[tid];

    // poll: waves 6,7 -> partner halves 0,1
    int* pflag = &flags[(b * 2 + (1 - r)) * 2 + ((tid - 384) >> 6)];

    float az0 = 0.f, az1 = 0.f, az2 = 0.f;     // A(t0+tl-1) at CA(tl); loaded in-loop
    float xv = 0.f;
    __syncthreads();   // prologue LDS visible

    for (int tl = 0; tl < TC; ++tl) {
        const int t = t0 + tl;

        // ======== phase CA: gates(t-1)+publish | KAN(t) | poll h(t-1) | x(t+1) issue ========
        if (pstate) {
            if (tl > 0) {
                float z0 = az0, z1 = az1, z2 = az2;
#pragma unroll
                for (int q = 0; q < 4; ++q) {
                    z0 += zred[w + q][lane][0];
                    z1 += zred[w + q][lane][1];
                    z2 += zred[w + q][lane][2];
                }
                float ig = sigm(z0);
                float fg = sigm(z1);
                c_reg = fg * c_reg + ig * tanh_fast(z2);
                float og = sigm(so_l[0] * aw0 + so_l[1] * aw1 + so_l[2] * aw2 + ab);
                float hn = og * tanh_fast(c_reg);
                hs[ui] = hn;
                hhist[tl - 1][c] = hn;
                // publish h(t-1): write-through stores + wave-local drain + half-flag
                __hip_atomic_store(&xh[((size_t)b * 2 + ((t - 1) & 1)) * 256 + ui], hn,
                                   __ATOMIC_RELAXED, __HIP_MEMORY_SCOPE_SYSTEM);
                asm volatile("s_waitcnt vmcnt(0)" ::: "memory");
                if (lane == 0)
                    __hip_atomic_store(&flags[(b * 2 + r) * 2 + (w >> 2)], t - 1,
                                       __ATOMIC_RELAXED, __HIP_MEMORY_SCOPE_SYSTEM);
            }
            // A(t) prefetch for gates at CA(tl+1) -- AFTER flag so publish drain
            // covers only the xh stores.
            const float* Ap = A + ((size_t)b * TC + tl) * TU + ui;
            az0 = Ap[0]; az1 = Ap[256]; az2 = Ap[512];
        }
        if (u1i >= 0) {                           // x(t+1) issue (stage at B)
            int tn = (t + 1 < T_) ? t + 1 : t;
            xv = X[((size_t)b * T_ + tn) * D_ + u1i];
        }
        {                                         // KAN u0 (reads xs(t), subs)
            float a0 = xs[d0] * skx0 + subs[s0] * skh0;
            kred[tid] = a0 * sigm(a0) * bw0 + spline_eval(a0, ksw_lds, tid);
        }
        if (u1i >= 0) {                           // KAN u1
            float a1 = xs[u1i] * skx1 + subs[2] * skh1;
            kred[512 + u1i] = a1 * sigm(a1) * bw1 + spline_eval(a1, ksw_lds, 512 + u1i);
        }
        if (tl > 0 && tid >= 384) {               // waves 6,7: poll + fetch partner h(t-1)
            const int uidx = (1 - r) * 128 + (tid - 384);
            while (__hip_atomic_load(pflag, __ATOMIC_RELAXED, __HIP_MEMORY_SCOPE_SYSTEM) < t - 1) {}
            asm volatile("" ::: "memory");
            hs[uidx] = __hip_atomic_load(&xh[((size_t)b * 2 + ((t - 1) & 1)) * 256 + uidx],
                                         __ATOMIC_RELAXED, __HIP_MEMORY_SCOPE_SYSTEM);
        }
        __syncthreads();   // syncCA: hs(t-1) complete + kred visible

        // ======== phase B: GEMV(t) | KAN reduce(t) | stage xs(t+1) ========
        {
            const float* hp = &hs[p * 64];
            float a0 = 0.f, a1 = 0.f, a2 = 0.f;
#pragma unroll
            for (int j = 0; j < 16; ++j) {
                float4 h4 = *(const float4*)(hp + j * 4);   // uniform addr -> LDS broadcast
                a0 = fmaf(h4.x, Rf[0][j * 4 + 0], a0);
                a1 = fmaf(h4.x, Rf[1][j * 4 + 0], a1);
                a2 = fmaf(h4.x, Rf[2][j * 4 + 0], a2);
                a0 = fmaf(h4.y, Rf[0][j * 4 + 1], a0);
                a1 = fmaf(h4.y, Rf[1][j * 4 + 1], a1);
                a2 = fmaf(h4.y, Rf[2][j * 4 + 1], a2);
                a0 = fmaf(h4.z, Rf[0][j * 4 + 2], a0);
                a1 = fmaf(h4.z, Rf[1][j * 4 + 2], a1);
                a2 = fmaf(h4.z, Rf[2][j * 4 + 2], a2);
                a0 = fmaf(h4.w, Rf[0][j * 4 + 3], a0);
                a1 = fmaf(h4.w, Rf[1][j * 4 + 3], a1);
                a2 = fmaf(h4.w, Rf[2][j * 4 + 3], a2);
            }
            zred[w][lane][0] = a0;
            zred[w][lane][1] = a1;
            zred[w][lane][2] = a2;
        }
        if (w < 3) {                              // KAN reduce (kred from syncCA)
            float v = kred[w * 256 + lane] + kred[w * 256 + 64 + lane]
                    + kred[w * 256 + 128 + lane] + kred[w * 256 + 192 + lane];
#pragma unroll
            for (int m = 32; m > 0; m >>= 1) v += __shfl_xor(v, m, 64);
            if (lane == 0) {
                so_l[w] = v;
                subs[w] = st2[w * 2] * v + st2[w * 2 + 1] * subs[w];
            }
        }
        if (u1i >= 0) xs[u1i] = xv;               // stage x(t+1)
        __syncthreads();   // syncB: zred/so_l/subs/xs(t+1) visible
    }

    // ---- epilogue: final gates (step t0+TC-1), then bulk out-write ----
    if (pstate) {
        float z0 = az0, z1 = az1, z2 = az2;       // az = A(t0+TC-1)
#pragma unroll
        for (int q = 0; q < 4; ++q) {
            z0 += zred[w + q][lane][0];
            z1 += zred[w + q][lane][1];
            z2 += zred[w + q][lane][2];
        }
        float ig = sigm(z0);
        float fg = sigm(z1);
        c_reg = fg * c_reg + ig * tanh_fast(z2);
        float og = sigm(so_l[0] * aw0 + so_l[1] * aw1 + so_l[2] * aw2 + ab);
        float hn = og * tanh_fast(c_reg);
        hhist[TC - 1][c] = hn;
        ws_h[b * 256 + ui] = hn;
        ws_c[b * 256 + ui] = c_reg;
    }
    __syncthreads();
    for (int i = tid; i < TC * 128; i += 512) {
        int tl = i >> 7, cc = i & 127;
        out[((size_t)b * T_ + t0 + tl) * U_ + r * 128 + cc] = hhist[tl][cc];
    }
    if (tid < 3) ws_sub[b * 3 + tid] = subs[tid];
}

extern "C" void kernel_launch(void* const* d_in, const int* in_sizes, int n_in,
                              void* d_out, int out_size, void* d_ws, size_t ws_size,
                              hipStream_t stream) {
    const float* x    = (const float*)d_in[0];
    const float* Kmat = (const float*)d_in[1];
    const float* R    = (const float*)d_in[2];
    const float* bias = (const float*)d_in[3];
    const float* stk  = (const float*)d_in[4];
    const float* strk = (const float*)d_in[5];
    const float* aggw = (const float*)d_in[6];
    const float* aggb = (const float*)d_in[7];
    const float* kbw  = (const float*)d_in[8];
    const float* ksw  = (const float*)d_in[9];
    float* out = (float*)d_out;

    float* ws   = (float*)d_ws;
    float* A    = ws;                             // 6,291,456 floats (24 MB)
    float* wh   = A + (size_t)B_ * TC * TU;       // 32768
    float* wc   = wh + B_ * U_;                   // 32768
    float* wsub = wc + B_ * U_;                   // 384 (pad to 512)
    float* xh   = wsub + 512;                     // B*2*256 = 65536
    int*   flg  = (int*)(xh + (size_t)B_ * 2 * 256);  // 512 ints [B][2][2]

    k0_init<<<dim3(B_), dim3(256), 0, stream>>>(wh, wc, wsub, flg);
    for (int ci = 0; ci < NC; ++ci) {
        k1_gemm<<<dim3((B_ * TC) / M1, TU / N1), dim3(256), 0, stream>>>(x, Kmat, bias, A, ci * TC);
        k2_rec<<<dim3(2 * B_), dim3(512), 0, stream>>>(A, x, R, stk, strk, aggw, aggb, kbw, ksw,
                                                       out, wh, wc, wsub, xh, flg, ci * TC);
    }
}

// Round 9
// 802.102 us; speedup vs baseline: 1.4204x; 1.4204x over previous
//
#include <hip/hip_runtime.h>

#define B_  128
#define T_  256
#define D_  256
#define U_  256
#define TU  768      // 3*U
#define TC  64       // timestep chunk
#define NC  (T_/TC)  // 4 chunks

__device__ __forceinline__ float sigm(float x) { return 1.f / (1.f + __expf(-x)); }

// tanh via __expf: tanh(x) = 1 - 2/(e^{2x}+1). (absmax unchanged since R2)
__device__ __forceinline__ float tanh_fast(float x) {
    float e = __expf(2.f * x);
    return 1.f - 2.f / (e + 1.f);
}

// direct cubic B-spline eval: grid cells [g_j, g_j+0.4), g_j = -2.2 + 0.4*j, j=0..10
// nonzero basis m = j-3..j (clipped to 0..7); coeffs at ksw_lds[u*9 + m]
__device__ __forceinline__ float spline_eval(float x, const float* __restrict__ ksw_lds, int u) {
    float xc = (x + 2.2f) * 2.5f;
    float fj = floorf(xc);
    int   j  = (int)fj;
    float tl = xc - fj;
    float t2 = tl * tl, t3 = t2 * tl;
    float om = 1.f - tl;
    const float S = 1.f / 6.f;
    float w0 = om * om * om * S;                            // m = j-3
    float w1 = (3.f * t3 - 6.f * t2 + 4.f) * S;             // m = j-2
    float w2 = (-3.f * t3 + 3.f * t2 + 3.f * tl + 1.f) * S; // m = j-1
    float w3 = t3 * S;                                      // m = j
    bool  v  = (j >= 0) && (j <= 10);
    float r  = 0.f;
#pragma unroll
    for (int k = 0; k < 4; ++k) {
        int   m  = j - 3 + k;
        bool  ok = v && (m >= 0) && (m <= 7);
        int   mc = min(max(m, 0), 7);
        float wk = (k == 0) ? w0 : (k == 1) ? w1 : (k == 2) ? w2 : w3;
        float cf = ksw_lds[u * 9 + mc];
        r += ok ? wk * cf : 0.f;
    }
    return r;
}

// ---------------- K0: zero recurrent state + poison xh tags ----------------
// xh words pre-set to 0x00000001 (tag bit = 1). First expected tags are 0,
// so garbage can never false-match the sentinel poll.
__global__ void k0_init(float* __restrict__ wh, float* __restrict__ wc,
                        float* __restrict__ wsub, float* __restrict__ xh) {
    int i = blockIdx.x * 256 + threadIdx.x;          // grid 128 -> 32768
    wh[i] = 0.f;
    wc[i] = 0.f;
    ((int*)xh)[i]         = 1;
    ((int*)xh)[i + 32768] = 1;
    if (i < 3 * B_) wsub[i] = 0.f;
}

// ---------------- K1: A[b][tl][j] = x[b, t0+tl, :] @ kernel + bias ----------------
// Proven 64x64-tile version (~57 us).
__global__ __launch_bounds__(256) void k1_gemm(const float* __restrict__ X,
                                               const float* __restrict__ Km,
                                               const float* __restrict__ bias,
                                               float* __restrict__ A, int t0) {
    __shared__ float Xs[16][68];
    __shared__ float Ks[16][68];
    const int bm  = blockIdx.x * 64;
    const int bn  = blockIdx.y * 64;
    const int tid = threadIdx.x;
    const int ty = tid >> 4, tx = tid & 15;

    const int lr  = tid >> 2;
    const int lk4 = (tid & 3) * 4;
    const int rr  = bm + lr;
    const int b   = rr >> 6;
    const int tl  = rr & 63;
    const float* xrow = X + (size_t)(b * T_ + t0 + tl) * D_;

    const int kr  = tid >> 4;
    const int kn4 = (tid & 15) * 4;

    float acc[4][4] = {};
    for (int kb = 0; kb < 256; kb += 16) {
        float4 xv = *(const float4*)(xrow + kb + lk4);
        Xs[lk4 + 0][lr] = xv.x;
        Xs[lk4 + 1][lr] = xv.y;
        Xs[lk4 + 2][lr] = xv.z;
        Xs[lk4 + 3][lr] = xv.w;
        *(float4*)&Ks[kr][kn4] = *(const float4*)(Km + (size_t)(kb + kr) * TU + bn + kn4);
        __syncthreads();
#pragma unroll
        for (int k = 0; k < 16; ++k) {
            float4 av = *(float4*)&Xs[k][ty * 4];
            float4 bv = *(float4*)&Ks[k][tx * 4];
            acc[0][0] += av.x * bv.x; acc[0][1] += av.x * bv.y; acc[0][2] += av.x * bv.z; acc[0][3] += av.x * bv.w;
            acc[1][0] += av.y * bv.x; acc[1][1] += av.y * bv.y; acc[1][2] += av.y * bv.z; acc[1][3] += av.y * bv.w;
            acc[2][0] += av.z * bv.x; acc[2][1] += av.z * bv.y; acc[2][2] += av.z * bv.z; acc[2][3] += av.z * bv.w;
            acc[3][0] += av.w * bv.x; acc[3][1] += av.w * bv.y; acc[3][2] += av.w * bv.z; acc[3][3] += av.w * bv.w;
        }
        __syncthreads();
    }
    float4 bv = *(const float4*)(bias + bn + tx * 4);
#pragma unroll
    for (int i = 0; i < 4; ++i) {
        float4 o;
        o.x = acc[i][0] + bv.x; o.y = acc[i][1] + bv.y;
        o.z = acc[i][2] + bv.z; o.w = acc[i][3] + bv.w;
        *(float4*)(A + (size_t)(bm + ty * 4 + i) * TU + bn + tx * 4) = o;
    }
}

// ---------------- K2: pair-split recurrence, R stationary in regs ----------------
// R7 2-barrier structure + flag-free sentinel exchange (R8) + ROUND 9 BUGFIX:
// R8 skipped the xh publish for each chunk's LAST step (s = t0+63, routed to
// ws_h only), breaking the per-word tag alternation at chunk boundaries:
// buffer-1 words went ...s=61(tag0), [63 skipped], 65(tag0)... -> the poll for
// s=65 could false-match the stale s=61 value (absmax 0.42). Fix: epilogue
// ALSO publishes the tagged h(t0+63) to xh. Tag sequence per word is then
// globally alternating; cross-dispatch ordering (stream serialization) makes
// the boundary poll safe, and per-location coherence + the <=1-step mutual
// skew bound make in-chunk polls safe.
__global__ __launch_bounds__(512, 2)
void k2_rec(const float* __restrict__ A,
            const float* __restrict__ X,
            const float* __restrict__ R,
            const float* __restrict__ stk,
            const float* __restrict__ strk,
            const float* __restrict__ aggw,
            const float* __restrict__ aggb,
            const float* __restrict__ kbw,
            const float* __restrict__ ksw,
            float* __restrict__ out,
            float* __restrict__ ws_h,
            float* __restrict__ ws_c,
            float* __restrict__ ws_sub,
            float* __restrict__ xh,    // [B][2][256], sentinel-tagged
            int t0) {
    __shared__ float hs[256];
    __shared__ float xs[256];
    __shared__ float zred[8][64][3];
    __shared__ float kred[768];
    __shared__ float so_l[3];
    __shared__ float subs[3];
    __shared__ float st2[6];
    __shared__ float hhist[TC][128];        // 32 KB h history -> epilogue bulk write
    __shared__ float ksw_lds[768 * 9];

    const int tid  = threadIdx.x;
    const int lane = tid & 63;
    const int w    = tid >> 6;
    const int p    = w & 3;
    const int c    = ((w >> 2) << 6) | lane;   // 0..127
    const int b    = blockIdx.x & 127;
    const int r    = blockIdx.x >> 7;
    const int ui   = r * 128 + c;              // global output-unit index
    const bool pstate = (p == 0);              // waves 0 and 4 hold gate state

    // ---- stationary R fragment (lives in unified VGPR/AGPR file) ----
    float Rf[3][64];
#pragma unroll
    for (int g = 0; g < 3; ++g)
#pragma unroll
        for (int uu = 0; uu < 64; ++uu)
            Rf[g][uu] = R[(size_t)(p * 64 + uu) * TU + g * 256 + ui];

    // ---- KAN duties: u0 = tid for ALL; u1 + x-prefetch on waves 1,2,3,5 ----
    const int s0 = tid >> 8, d0 = tid & 255;
    const float skx0 = strk[s0 * 512 + d0];
    const float skh0 = strk[s0 * 512 + 256 + d0];
    const float bw0  = kbw[tid];
    int u1i = -1;
    if (tid >= 64 && tid < 256)       u1i = tid - 64;    // waves 1-3 -> 0..191
    else if (tid >= 320 && tid < 384) u1i = tid - 128;   // wave 5    -> 192..255
    float skx1 = 0.f, skh1 = 0.f, bw1 = 0.f;
    if (u1i >= 0) {
        skx1 = strk[2 * 512 + u1i];
        skh1 = strk[2 * 512 + 256 + u1i];
        bw1  = kbw[512 + u1i];
    }

    const float aw0 = aggw[ui], aw1 = aggw[256 + ui], aw2 = aggw[512 + ui], ab = aggb[ui];
    float c_reg = ws_c[b * 256 + ui];

    for (int i = tid; i < 768 * 8; i += 512) ksw_lds[(i >> 3) * 9 + (i & 7)] = ksw[i];
    if (tid < 256) hs[tid] = ws_h[b * 256 + tid];
    if (tid < 256) xs[tid] = X[((size_t)b * T_ + t0) * D_ + tid];
    if (tid < 3)   subs[tid] = ws_sub[b * 3 + tid];
    if (tid < 6)   st2[tid] = stk[tid];

    float az0 = 0.f, az1 = 0.f, az2 = 0.f;     // A(t-1) for gates at CA(tl)
    float xv = 0.f;
    __syncthreads();   // prologue LDS visible

    for (int tl = 0; tl < TC; ++tl) {
        const int t = t0 + tl;

        // ======== phase CA: gates(t-1)+publish | KAN(t) | poll h(t-1) | x(t+1) ========
        if (pstate) {
            if (tl > 0) {
                float z0 = az0, z1 = az1, z2 = az2;
#pragma unroll
                for (int q = 0; q < 4; ++q) {
                    z0 += zred[w + q][lane][0];
                    z1 += zred[w + q][lane][1];
                    z2 += zred[w + q][lane][2];
                }
                float ig = sigm(z0);
                float fg = sigm(z1);
                c_reg = fg * c_reg + ig * tanh_fast(z2);
                float og = sigm(so_l[0] * aw0 + so_l[1] * aw1 + so_l[2] * aw2 + ab);
                float hn = og * tanh_fast(c_reg);
                hs[ui] = hn;
                hhist[tl - 1][c] = hn;
                // sentinel publish of h(s), s = t-1: low mantissa bit := (s>>1)&1.
                // Fire-and-forget: no drain, no flag. Data self-announces.
                unsigned hb = (__float_as_uint(hn) & ~1u) | (unsigned)(((t - 1) >> 1) & 1);
                __hip_atomic_store((unsigned*)&xh[((size_t)b * 2 + ((t - 1) & 1)) * 256 + ui],
                                   hb, __ATOMIC_RELAXED, __HIP_MEMORY_SCOPE_SYSTEM);
            }
            // A(t) prefetch for gates at CA(tl+1)
            const float* Ap = A + ((size_t)b * TC + tl) * TU + ui;
            az0 = Ap[0]; az1 = Ap[256]; az2 = Ap[512];
        }
        if (u1i >= 0) {                           // x(t+1) issue (stage at B)
            int tn = (t + 1 < T_) ? t + 1 : t;
            xv = X[((size_t)b * T_ + tn) * D_ + u1i];
        }
        {                                         // KAN u0 (reads xs(t), subs)
            float a0 = xs[d0] * skx0 + subs[s0] * skh0;
            kred[tid] = a0 * sigm(a0) * bw0 + spline_eval(a0, ksw_lds, tid);
        }
        if (u1i >= 0) {                           // KAN u1
            float a1 = xs[u1i] * skx1 + subs[2] * skh1;
            kred[512 + u1i] = a1 * sigm(a1) * bw1 + spline_eval(a1, ksw_lds, 512 + u1i);
        }
        if (tl > 0 && tid >= 384) {               // waves 6,7: sentinel poll = data fetch
            const int uidx = (1 - r) * 128 + (tid - 384);
            const unsigned expect = (unsigned)(((t - 1) >> 1) & 1);
            const unsigned* src = (const unsigned*)&xh[((size_t)b * 2 + ((t - 1) & 1)) * 256 + uidx];
            unsigned v;
            do {
                v = __hip_atomic_load(src, __ATOMIC_RELAXED, __HIP_MEMORY_SCOPE_SYSTEM);
            } while ((v & 1u) != expect);
            hs[uidx] = __uint_as_float(v);
        }
        __syncthreads();   // syncCA: hs(t-1) complete + kred visible

        // ======== phase B: GEMV(t) | KAN reduce(t) | stage xs(t+1) ========
        {
            const float* hp = &hs[p * 64];
            float a0 = 0.f, a1 = 0.f, a2 = 0.f;
#pragma unroll
            for (int j = 0; j < 16; ++j) {
                float4 h4 = *(const float4*)(hp + j * 4);   // uniform addr -> LDS broadcast
                a0 = fmaf(h4.x, Rf[0][j * 4 + 0], a0);
                a1 = fmaf(h4.x, Rf[1][j * 4 + 0], a1);
                a2 = fmaf(h4.x, Rf[2][j * 4 + 0], a2);
                a0 = fmaf(h4.y, Rf[0][j * 4 + 1], a0);
                a1 = fmaf(h4.y, Rf[1][j * 4 + 1], a1);
                a2 = fmaf(h4.y, Rf[2][j * 4 + 1], a2);
                a0 = fmaf(h4.z, Rf[0][j * 4 + 2], a0);
                a1 = fmaf(h4.z, Rf[1][j * 4 + 2], a1);
                a2 = fmaf(h4.z, Rf[2][j * 4 + 2], a2);
                a0 = fmaf(h4.w, Rf[0][j * 4 + 3], a0);
                a1 = fmaf(h4.w, Rf[1][j * 4 + 3], a1);
                a2 = fmaf(h4.w, Rf[2][j * 4 + 3], a2);
            }
            zred[w][lane][0] = a0;
            zred[w][lane][1] = a1;
            zred[w][lane][2] = a2;
        }
        if (w < 3) {                              // KAN reduce (kred from syncCA)
            float v = kred[w * 256 + lane] + kred[w * 256 + 64 + lane]
                    + kred[w * 256 + 128 + lane] + kred[w * 256 + 192 + lane];
#pragma unroll
            for (int m = 32; m > 0; m >>= 1) v += __shfl_xor(v, m, 64);
            if (lane == 0) {
                so_l[w] = v;
                subs[w] = st2[w * 2] * v + st2[w * 2 + 1] * subs[w];
            }
        }
        if (u1i >= 0) xs[u1i] = xv;               // stage x(t+1)
        __syncthreads();   // syncB: zred/so_l/subs/xs(t+1) visible
    }

    // ---- epilogue: final gates (step s = t0+TC-1), then bulk out-write ----
    if (pstate) {
        float z0 = az0, z1 = az1, z2 = az2;       // az = A(t0+TC-1)
#pragma unroll
        for (int q = 0; q < 4; ++q) {
            z0 += zred[w + q][lane][0];
            z1 += zred[w + q][lane][1];
            z2 += zred[w + q][lane][2];
        }
        float ig = sigm(z0);
        float fg = sigm(z1);
        c_reg = fg * c_reg + ig * tanh_fast(z2);
        float og = sigm(so_l[0] * aw0 + so_l[1] * aw1 + so_l[2] * aw2 + ab);
        float hn = og * tanh_fast(c_reg);
        hhist[TC - 1][c] = hn;
        ws_h[b * 256 + ui] = hn;                  // exact value for next chunk's prologue
        ws_c[b * 256 + ui] = c_reg;
        // ROUND 9 FIX: ALSO publish tagged h(s), s = t0+TC-1, so the per-word
        // tag alternation is unbroken across chunk boundaries (R8's bug).
        {
            const int s = t0 + TC - 1;
            unsigned hb = (__float_as_uint(hn) & ~1u) | (unsigned)(((s) >> 1) & 1);
            __hip_atomic_store((unsigned*)&xh[((size_t)b * 2 + (s & 1)) * 256 + ui],
                               hb, __ATOMIC_RELAXED, __HIP_MEMORY_SCOPE_SYSTEM);
        }
    }
    __syncthreads();
    for (int i = tid; i < TC * 128; i += 512) {
        int tl = i >> 7, cc = i & 127;
        out[((size_t)b * T_ + t0 + tl) * U_ + r * 128 + cc] = hhist[tl][cc];
    }
    if (tid < 3) ws_sub[b * 3 + tid] = subs[tid];
}

extern "C" void kernel_launch(void* const* d_in, const int* in_sizes, int n_in,
                              void* d_out, int out_size, void* d_ws, size_t ws_size,
                              hipStream_t stream) {
    const float* x    = (const float*)d_in[0];
    const float* Kmat = (const float*)d_in[1];
    const float* R    = (const float*)d_in[2];
    const float* bias = (const float*)d_in[3];
    const float* stk  = (const float*)d_in[4];
    const float* strk = (const float*)d_in[5];
    const float* aggw = (const float*)d_in[6];
    const float* aggb = (const float*)d_in[7];
    const float* kbw  = (const float*)d_in[8];
    const float* ksw  = (const float*)d_in[9];
    float* out = (float*)d_out;

    float* ws   = (float*)d_ws;
    float* A    = ws;                             // 6,291,456 floats (24 MB)
    float* wh   = A + (size_t)B_ * TC * TU;       // 32768
    float* wc   = wh + B_ * U_;                   // 32768
    float* wsub = wc + B_ * U_;                   // 384 (pad to 512)
    float* xh   = wsub + 512;                     // B*2*256 = 65536

    k0_init<<<dim3(B_), dim3(256), 0, stream>>>(wh, wc, wsub, xh);
    for (int ci = 0; ci < NC; ++ci) {
        k1_gemm<<<dim3((B_ * TC) / 64, TU / 64), dim3(256), 0, stream>>>(x, Kmat, bias, A, ci * TC);
        k2_rec<<<dim3(2 * B_), dim3(512), 0, stream>>>(A, x, R, stk, strk, aggw, aggb, kbw, ksw,
                                                       out, wh, wc, wsub, xh, ci * TC);
    }
}